// Round 3
// baseline (242.476 us; speedup 1.0000x reference)
//
#include <hip/hip_runtime.h>

typedef __bf16 bf16;
typedef __bf16 bf16x4 __attribute__((ext_vector_type(4)));
typedef __bf16 bf16x8 __attribute__((ext_vector_type(8)));
typedef float f32x4 __attribute__((ext_vector_type(4)));

#define T_SEQ 2048
#define QK_LD 2048

extern "C" __device__ float __ocml_native_exp2_f32(float);   // raw v_exp_f32

#define GLOAD16(gp, lp)                                                        \
  __builtin_amdgcn_global_load_lds(                                            \
      (const __attribute__((address_space(1))) unsigned int*)(gp),             \
      (__attribute__((address_space(3))) unsigned int*)(lp), 16, 0, 0)

// ---------------------------------------------------------------------------
// Fused prep (one dispatch, 256-thr blocks):
//   blocks [0, 8192)        : x (fp32, 8192x1024) -> xb bf16
//   blocks [8192, 8192+3072): W_qkv (1024x3072) -> wtq (3072x1024) bf16
//   blocks [+3072, +4096)   : W_out (1024x1024) -> wto (1024x1024) bf16
// ---------------------------------------------------------------------------
__global__ void prep_kernel(const float* __restrict__ x, bf16* __restrict__ xb,
                            const float* __restrict__ Wq, bf16* __restrict__ Wtq,
                            const float* __restrict__ Wo, bf16* __restrict__ Wto) {
    __shared__ float tile[32][33];
    const int t = threadIdx.x;
    if (blockIdx.x < 8192) {
        const int i = (blockIdx.x * 256 + t) * 4;
        const float4 f = *(const float4*)(x + i);
        bf16x4 o;
        o.x = (bf16)f.x; o.y = (bf16)f.y; o.z = (bf16)f.z; o.w = (bf16)f.w;
        *(bf16x4*)(xb + i) = o;
        return;
    }
    const int bid = blockIdx.x - 8192;            // [0, 4096)
    const int xblk = bid & 127, yblk = bid >> 7;  // 128 x 32 tiles of 32x32
    const bool isQ = xblk < 96;
    const float* W = isQ ? Wq : Wo;
    bf16* Wt = isQ ? Wtq : Wto;
    const int C = isQ ? 3072 : 1024;
    const int R = 1024;
    const int bx = (isQ ? xblk : (xblk - 96)) * 32;
    const int by = yblk * 32;
    const int tx = t & 31, ty = t >> 5;
#pragma unroll
    for (int i = 0; i < 32; i += 8)
        tile[ty + i][tx] = W[(size_t)(by + ty + i) * C + bx + tx];
    __syncthreads();
#pragma unroll
    for (int i = 0; i < 32; i += 8)
        Wt[(size_t)(bx + ty + i) * R + by + tx] = (bf16)tile[tx][ty + i];
}

// ---------------------------------------------------------------------------
// 256x256 GEMM, round-2 restructure: SINGLE-BARRIER K-TILE, free-scheduled
// body. Round-1 post-mortem: 8 s_barrier + 3 vmcnt + 8 sched_barrier(0) per
// K-tile cost ~3100 cyc/K-tile of pure serialization (5590 measured vs 2483
// MFMA floor) — the m141 "over-pinning" failure mode. Within a K-tile no LDS
// write touches the buffer being read (stages go to buf^1), so intra-tile
// barriers are correctness-dead. New structure per K-tile:
//   { stage all 4 halves of kt+1 -> buf^1 (8 global_load_lds);
//     read 24 frags from buf (ds_read_b128, XOR-swizzled, conflict-free);
//     64 MFMA (ks outermost for dep spacing);
//     s_waitcnt vmcnt(0); s_barrier; sched_barrier(0) }
// vmcnt(0) here is cheap: drained loads were issued a full tile (~2500 cyc)
// earlier (not the m97 issue-then-drain stall). Race-safety: each wave's
// ds_reads are lgkm-consumed by its own MFMAs before it reaches the barrier,
// so next-tile stage-writes (issued after the barrier) can't clobber un-read
// data. Compiler now interleaves ds_read latency under the MFMA stream.
// ---------------------------------------------------------------------------
template <bool OUT_BF16, bool SPLIT_V>
__global__ __launch_bounds__(512, 2)
void gemm256(const bf16* __restrict__ A, const bf16* __restrict__ Bt,
             const float* __restrict__ bias, void* __restrict__ Cout,
             bf16* __restrict__ Vtb, int M, int N, int K, int ldC) {
    __shared__ bf16 sm[65536];   // 128 KiB

    const int t = threadIdx.x;
    const int lane = t & 63, quad = lane >> 4, l16 = lane & 15;
    const int wv = t >> 6;
    const int wm = (wv >> 2) * 64;   // row base within an A half (2 M-wave-groups)
    const int wn = (wv & 3) * 32;    // row base within a B half (4 N-wave-groups)
    const long m0 = (long)blockIdx.y * 256;
    const long n0 = (long)blockIdx.x * 256;
    (void)M; (void)N;

    f32x4 acc[2][2][4][2] = {};      // [mq][nq][i][j]

    // --- staging source coords: linear chunk l = q*512 + t ------------------
    // row = q*64 + (t>>3); stored chunk c' = t&7 holds logical c = c'^(row&7)
    const int srow = t >> 3;
    const int scol = ((t & 7) ^ ((t >> 3) & 7)) * 8;
    const bf16* agp = A  + (m0 + srow) * (long)K + scol;
    const bf16* bgp = Bt + (n0 + srow) * (long)K + scol;
    const long rowK64  = (long)64 * K;
    const long rowK128 = (long)128 * K;
    bf16* ldst = sm + wv * 512;      // + buf*32768 + oper*16384 + half*8192 + q*4096

    auto stage = [&](int buf, int oper, int half, int kt) {
        const bf16* src = (oper ? bgp : agp) + (long)kt * 64 + (half ? rowK128 : 0);
        bf16* dst = ldst + buf * 32768 + oper * 16384 + half * 8192;
        GLOAD16(src, dst);                      // rows [0,64) of the half
        GLOAD16(src + rowK64, dst + 4096);      // rows [64,128)
    };

    // --- fragment LDS offsets (within a half base) --------------------------
    int offA[4][2], offB[2][2];
#pragma unroll
    for (int i = 0; i < 4; ++i)
#pragma unroll
        for (int ks = 0; ks < 2; ++ks) {
            const int r = wm + i * 16 + l16;
            offA[i][ks] = r * 64 + (((ks * 4 + quad) ^ (r & 7)) << 3);
        }
#pragma unroll
    for (int j = 0; j < 2; ++j)
#pragma unroll
        for (int ks = 0; ks < 2; ++ks) {
            const int r = wn + j * 16 + l16;
            offB[j][ks] = r * 64 + (((ks * 4 + quad) ^ (r & 7)) << 3);
        }

    const int nkt = K >> 6;          // K-tiles of 64

    // prologue: stage tile 0 into buf0, full drain, barrier
    stage(0, 0, 0, 0);
    stage(0, 1, 0, 0);
    stage(0, 0, 1, 0);
    stage(0, 1, 1, 0);
    asm volatile("s_waitcnt vmcnt(0)" ::: "memory");
    __builtin_amdgcn_s_barrier();
    __builtin_amdgcn_sched_barrier(0);

    for (int kt = 0; kt < nkt; ++kt) {
        const int buf = kt & 1;
        if (kt + 1 < nkt) {          // stage next tile early (independent)
            stage(buf ^ 1, 0, 0, kt + 1);
            stage(buf ^ 1, 1, 0, kt + 1);
            stage(buf ^ 1, 0, 1, kt + 1);
            stage(buf ^ 1, 1, 1, kt + 1);
        }
        const bf16* base_ = sm + buf * 32768;
        bf16x8 fA[2][2][4];          // [mq][ks][i]
        bf16x8 fB[2][2][2];          // [nq][ks][j]
#pragma unroll
        for (int mq = 0; mq < 2; ++mq) {
            const bf16* sa_ = base_ + mq * 8192;
#pragma unroll
            for (int ks = 0; ks < 2; ++ks)
#pragma unroll
                for (int i = 0; i < 4; ++i)
                    fA[mq][ks][i] = *(const bf16x8*)(sa_ + offA[i][ks]);
        }
#pragma unroll
        for (int nq = 0; nq < 2; ++nq) {
            const bf16* sb_ = base_ + 16384 + nq * 8192;
#pragma unroll
            for (int ks = 0; ks < 2; ++ks)
#pragma unroll
                for (int j = 0; j < 2; ++j)
                    fB[nq][ks][j] = *(const bf16x8*)(sb_ + offB[j][ks]);
        }
#pragma unroll
        for (int ks = 0; ks < 2; ++ks)
#pragma unroll
            for (int mq = 0; mq < 2; ++mq)
#pragma unroll
                for (int nq = 0; nq < 2; ++nq)
#pragma unroll
                    for (int i = 0; i < 4; ++i)
#pragma unroll
                        for (int j = 0; j < 2; ++j)
                            acc[mq][nq][i][j] = __builtin_amdgcn_mfma_f32_16x16x32_bf16(
                                fB[nq][ks][j], fA[mq][ks][i], acc[mq][nq][i][j], 0, 0, 0);
        if (kt + 1 < nkt) {
            asm volatile("s_waitcnt vmcnt(0)" ::: "memory");
            __builtin_amdgcn_s_barrier();
            __builtin_amdgcn_sched_barrier(0);
        }
    }

    // --- epilogue (same swapped-D mapping as before: col=m via l16, row=n) --
    bf16*  Cb = (bf16*)Cout;
    float* Cf = (float*)Cout;
    const bool vblock = SPLIT_V && (n0 >= 2048);
#pragma unroll
    for (int mq = 0; mq < 2; ++mq)
#pragma unroll
    for (int i = 0; i < 4; ++i) {
        const long gm = m0 + mq * 128 + wm + i * 16 + l16;
#pragma unroll
        for (int nq = 0; nq < 2; ++nq)
#pragma unroll
        for (int j = 0; j < 2; ++j) {
            const long n = n0 + nq * 128 + wn + j * 16 + quad * 4;
            const float4 bv = *(const float4*)(bias + n);
            float v[4];
#pragma unroll
            for (int r = 0; r < 4; ++r) v[r] = acc[mq][nq][i][j][r] + (&bv.x)[r];
            if (vblock) {
                const int bb = (int)(gm >> 11), tok = (int)(gm & 2047);
                const int nv = (int)(n - 2048);
                const int h = nv >> 6, d0 = nv & 63;
                bf16* dst = Vtb + ((size_t)(bb * 16 + h) * 64 + d0) * T_SEQ + tok;
#pragma unroll
                for (int r = 0; r < 4; ++r) dst[(size_t)r * T_SEQ] = (bf16)v[r];
            } else if (OUT_BF16) {
                bf16x4 o;
#pragma unroll
                for (int r = 0; r < 4; ++r) o[r] = (bf16)v[r];
                *(bf16x4*)(Cb + gm * ldC + n) = o;
            } else {
                float4 o;
#pragma unroll
                for (int r = 0; r < 4; ++r) (&o.x)[r] = v[r];
                *(float4*)(Cf + gm * ldC + n) = o;
            }
        }
    }
}

// ---------------------------------------------------------------------------
// OLD 128x128 GEMM — kept for the output projection (N=1024: a 256² grid
// would be only 128 blocks = half-idle GPU). [r6/r9 verbatim]
// ---------------------------------------------------------------------------
template <bool OUT_BF16, bool SPLIT_V>
__global__ __launch_bounds__(256, 3)
void gemm_bt(const bf16* __restrict__ A, const bf16* __restrict__ Bt,
             const float* __restrict__ bias, void* __restrict__ Cout,
             bf16* __restrict__ Vtb, int M, int N, int K, int ldC) {
    __shared__ bf16 sm[16384];   // 2 bufs x (A 4096 + B 4096 elems) = 32 KB

    const int t = threadIdx.x;
    const int lane = t & 63, quad = lane >> 4, l16 = lane & 15;
    const int wave = t >> 6;
    const int wm = (wave >> 1) * 64;
    const int wn = (wave & 1) * 64;
    const long m0 = (long)blockIdx.y * 128;
    const long n0 = (long)blockIdx.x * 128;

    f32x4 acc[4][4] = {};

    const int sr = t >> 2, sc = t & 3;
    const int swz  = (sr * 4 + (sc ^ ((sr >> 1) & 3))) * 8;
    const int swz2 = ((sr + 64) * 4 + (sc ^ ((sr >> 1) & 3))) * 8;
    const bf16* agp = A  + (m0 + sr) * (long)K + sc * 8;
    const bf16* bgp = Bt + (n0 + sr) * (long)K + sc * 8;
    const long rowK = (long)64 * K;

    int offA[4], offB[4];
#pragma unroll
    for (int i = 0; i < 4; ++i) {
        const int row = wm + i * 16 + l16;
        offA[i] = (row * 4 + (quad ^ ((row >> 1) & 3))) * 8;
    }
#pragma unroll
    for (int j = 0; j < 4; ++j) {
        const int row = wn + j * 16 + l16;
        offB[j] = 4096 + (row * 4 + (quad ^ ((row >> 1) & 3))) * 8;
    }

    uint4 s0a0, s0a1, s0b0, s0b1;
    uint4 s1a0, s1a1, s1b0, s1b1;

    auto load0 = [&](int k) {
        s0a0 = *(const uint4*)(agp + k);        s0a1 = *(const uint4*)(agp + rowK + k);
        s0b0 = *(const uint4*)(bgp + k);        s0b1 = *(const uint4*)(bgp + rowK + k);
    };
    auto load1 = [&](int k) {
        s1a0 = *(const uint4*)(agp + k);        s1a1 = *(const uint4*)(agp + rowK + k);
        s1b0 = *(const uint4*)(bgp + k);        s1b1 = *(const uint4*)(bgp + rowK + k);
    };
    auto write0 = [&]() {   // always buf0
        *(uint4*)(sm + swz)         = s0a0;  *(uint4*)(sm + swz2)        = s0a1;
        *(uint4*)(sm + 4096 + swz)  = s0b0;  *(uint4*)(sm + 4096 + swz2) = s0b1;
    };
    auto write1 = [&]() {   // always buf1
        bf16* base = sm + 8192;
        *(uint4*)(base + swz)         = s1a0;  *(uint4*)(base + swz2)        = s1a1;
        *(uint4*)(base + 4096 + swz)  = s1b0;  *(uint4*)(base + 4096 + swz2) = s1b1;
    };
    auto compute = [&](const bf16* s) {
        bf16x8 af[4], bfr[4];
#pragma unroll
        for (int i = 0; i < 4; ++i) af[i] = *(const bf16x8*)(s + offA[i]);
#pragma unroll
        for (int j = 0; j < 4; ++j) bfr[j] = *(const bf16x8*)(s + offB[j]);
#pragma unroll
        for (int i = 0; i < 4; ++i)
#pragma unroll
            for (int j = 0; j < 4; ++j)   // swapped: D row=n, col=m
                acc[i][j] = __builtin_amdgcn_mfma_f32_16x16x32_bf16(bfr[j], af[i], acc[i][j], 0, 0, 0);
    };

    const int nk = K >> 5;
    load0(0);
    load1(32);
    write0();
    load0(64);
    __syncthreads();

    for (int kk = 0; kk < nk; kk += 2) {
        if (kk + 1 < nk) {
            write1();
            if (kk + 3 < nk) load1((kk + 3) * 32);
        }
        compute(sm);
        if (kk + 1 < nk) {
            __syncthreads();
            if (kk + 2 < nk) {
                write0();
                if (kk + 4 < nk) load0((kk + 4) * 32);
            }
            compute(sm + 8192);
            if (kk + 2 < nk) __syncthreads();
        }
    }

    bf16*  Cb = (bf16*)Cout;
    float* Cf = (float*)Cout;
    const bool vblock = SPLIT_V && (n0 >= 2048);
#pragma unroll
    for (int i = 0; i < 4; ++i) {
        const long gm = m0 + wm + i * 16 + l16;
#pragma unroll
        for (int j = 0; j < 4; ++j) {
            const int nloc = wn + j * 16 + quad * 4;
            const long n = n0 + nloc;
            const float4 bv = *(const float4*)(bias + n);
            float v[4];
#pragma unroll
            for (int r = 0; r < 4; ++r) v[r] = acc[i][j][r] + (&bv.x)[r];
            if (vblock) {
                const int bb = (int)(gm >> 11), tok = (int)(gm & 2047);
                const int nv = (int)(n - 2048);
                const int h = nv >> 6, d0 = nv & 63;
                bf16* dst = Vtb + ((size_t)(bb * 16 + h) * 64 + d0) * T_SEQ + tok;
#pragma unroll
                for (int r = 0; r < 4; ++r) dst[(size_t)r * T_SEQ] = (bf16)v[r];
            } else if (OUT_BF16) {
                bf16x4 o;
#pragma unroll
                for (int r = 0; r < 4; ++r) o[r] = (bf16)v[r];
                *(bf16x4*)(Cb + gm * ldC + n) = o;
            } else {
                float4 o;
#pragma unroll
                for (int r = 0; r < 4; ++r) (&o.x)[r] = v[r];
                *(float4*)(Cf + gm * ldC + n) = o;
            }
        }
    }
}

// ---------------------------------------------------------------------------
// Causal flash attention  [r6/r9 verbatim — best measured ~75 us].
// ---------------------------------------------------------------------------
__global__ __launch_bounds__(256, 3)
void attn_kernel(const bf16* __restrict__ qk, const bf16* __restrict__ vtb,
                 bf16* __restrict__ Out) {
    const int bh = blockIdx.x;
    const int qt = 15 - (int)blockIdx.y;    // heavy tiles first
    const int b = bh >> 4, h = bh & 15;
    const int t = threadIdx.x;
    const int wave = t >> 6, lane = t & 63, quad = lane >> 4, l16 = lane & 15;
    const int wq = wave * 32;
    const int q0 = qt * 128;

    __shared__ bf16 Ks[2][4096];
    __shared__ bf16 VTs[2][4096];
    __shared__ bf16 Ps[8192];

    const bf16* Qg = qk + (size_t)b * T_SEQ * QK_LD + h * 64;
    const bf16* Kg = Qg + 1024;
    const bf16* vth = vtb + (size_t)bh * 64 * T_SEQ;

    for (int c = t; c < 1024; c += 256) {
        const int row = c >> 3, kb = c & 7;
        *(uint4*)(Ps + row * 64 + (((kb ^ (row & 7)) << 3))) =
            *(const uint4*)(Qg + (size_t)(q0 + row) * QK_LD + kb * 8);
    }
    __syncthreads();
    const float qsc = 0.125f * 1.4426950408889634f;
    bf16x8 qf[2][2];
#pragma unroll
    for (int jt = 0; jt < 2; ++jt)
#pragma unroll
        for (int s = 0; s < 2; ++s) {
            const int row = wq + jt * 16 + l16;
            bf16x8 v = *(const bf16x8*)(Ps + row * 64 + (((s * 4 + quad) ^ (row & 7)) << 3));
#pragma unroll
            for (int e = 0; e < 8; ++e) v[e] = (bf16)((float)v[e] * qsc);
            qf[jt][s] = v;
        }

    const int sr = t >> 3;
    const int skb = (t & 7) ^ (sr & 7);
    const bf16* kp0 = Kg + (size_t)sr * QK_LD + skb * 8;
    const bf16* kp1 = kp0 + (size_t)32 * QK_LD;
    const bf16* vp0 = vth + (size_t)sr * T_SEQ + skb * 8;
    const bf16* vp1 = vp0 + (size_t)32 * T_SEQ;

    int offKV[4][2];
#pragma unroll
    for (int it = 0; it < 4; ++it)
#pragma unroll
        for (int s = 0; s < 2; ++s) {
            const int row = it * 16 + l16;
            offKV[it][s] = row * 64 + (((s * 4 + quad) ^ (row & 7)) << 3);
        }

    f32x4 oacc[4][2] = {};
    float lsum[2] = {0.f, 0.f};
    const int nkt = qt * 2 + 2;

    uint4 kr0 = *(const uint4*)kp0, kr1 = *(const uint4*)kp1;
    uint4 vr0 = *(const uint4*)vp0, vr1 = *(const uint4*)vp1;

    for (int kt = 0; kt < nkt; ++kt) {
        const int k0 = kt * 64;
        bf16* kb_ = Ks[kt & 1];
        bf16* vb_ = VTs[kt & 1];
        *(uint4*)(kb_ + t * 8)        = kr0;
        *(uint4*)(kb_ + 2048 + t * 8) = kr1;
        *(uint4*)(vb_ + t * 8)        = vr0;
        *(uint4*)(vb_ + 2048 + t * 8) = vr1;
        __syncthreads();

        if (kt + 1 < nkt) {
            const int kn = k0 + 64;
            kr0 = *(const uint4*)(kp0 + (size_t)kn * QK_LD);
            kr1 = *(const uint4*)(kp1 + (size_t)kn * QK_LD);
            vr0 = *(const uint4*)(vp0 + kn);
            vr1 = *(const uint4*)(vp1 + kn);
        }

        f32x4 sacc[4][2] = {};
#pragma unroll
        for (int s = 0; s < 2; ++s) {
            bf16x8 kf[4];
#pragma unroll
            for (int it = 0; it < 4; ++it)
                kf[it] = *(const bf16x8*)(kb_ + offKV[it][s]);
#pragma unroll
            for (int it = 0; it < 4; ++it)
#pragma unroll
                for (int jt = 0; jt < 2; ++jt)
                    sacc[it][jt] = __builtin_amdgcn_mfma_f32_16x16x32_bf16(kf[it], qf[jt][s], sacc[it][jt], 0, 0, 0);
        }

        const bool need_mask = (kt >= 2 * qt);
#pragma unroll
        for (int it = 0; it < 4; ++it)
#pragma unroll
            for (int jt = 0; jt < 2; ++jt) {
                const int prow = wq + jt * 16 + l16;
                bf16x4 pb;
                if (need_mask) {
                    const int qrow = q0 + prow;
                    const int kbase = k0 + it * 16 + quad * 4;
#pragma unroll
                    for (int r = 0; r < 4; ++r) {
                        const float e = __ocml_native_exp2_f32(sacc[it][jt][r]);
                        const float p = (kbase + r > qrow) ? 0.f : e;
                        lsum[jt] += p;
                        pb[r] = (bf16)p;
                    }
                } else {
#pragma unroll
                    for (int r = 0; r < 4; ++r) {
                        const float p = __ocml_native_exp2_f32(sacc[it][jt][r]);
                        lsum[jt] += p;
                        pb[r] = (bf16)p;
                    }
                }
                *(bf16x4*)(Ps + prow * 64 +
                           (((it * 2 + (quad >> 1)) ^ (prow & 7)) << 3) + ((quad & 1) << 2)) = pb;
            }

#pragma unroll
        for (int s2 = 0; s2 < 2; ++s2) {
            bf16x8 vf[4], pf[2];
#pragma unroll
            for (int it2 = 0; it2 < 4; ++it2)
                vf[it2] = *(const bf16x8*)(vb_ + offKV[it2][s2]);
#pragma unroll
            for (int jt = 0; jt < 2; ++jt) {
                const int prow = wq + jt * 16 + l16;
                pf[jt] = *(const bf16x8*)(Ps + prow * 64 + (((s2 * 4 + quad) ^ (prow & 7)) << 3));
            }
#pragma unroll
            for (int it2 = 0; it2 < 4; ++it2)
#pragma unroll
                for (int jt = 0; jt < 2; ++jt)
                    oacc[it2][jt] = __builtin_amdgcn_mfma_f32_16x16x32_bf16(vf[it2], pf[jt], oacc[it2][jt], 0, 0, 0);
        }
    }

    float inv[2];
#pragma unroll
    for (int jt = 0; jt < 2; ++jt) {
        float l = lsum[jt];
        l += __shfl_xor(l, 16);
        l += __shfl_xor(l, 32);
        inv[jt] = 1.0f / l;
    }
#pragma unroll
    for (int it2 = 0; it2 < 4; ++it2)
#pragma unroll
        for (int jt = 0; jt < 2; ++jt) {
            bf16x4 ob;
#pragma unroll
            for (int r = 0; r < 4; ++r) ob[r] = (bf16)(oacc[it2][jt][r] * inv[jt]);
            const int qrow = q0 + wq + jt * 16 + l16;
            const int dcol = h * 64 + it2 * 16 + quad * 4;
            *(bf16x4*)&Out[(size_t)(b * T_SEQ + qrow) * 1024 + dcol] = ob;
        }
}

// ---------------------------------------------------------------------------
extern "C" void kernel_launch(void* const* d_in, const int* in_sizes, int n_in,
                              void* d_out, int out_size, void* d_ws, size_t ws_size,
                              hipStream_t stream) {
    const float* x     = (const float*)d_in[0];
    const float* W_qkv = (const float*)d_in[1];
    const float* b_qkv = (const float*)d_in[2];
    const float* W_out = (const float*)d_in[3];
    const float* b_out = (const float*)d_in[4];
    float* out = (float*)d_out;

    char* ws = (char*)d_ws;
    bf16* xb   = (bf16*)ws; ws += (size_t)8192 * 1024 * 2;
    bf16* wtq  = (bf16*)ws; ws += (size_t)3072 * 1024 * 2;
    bf16* wto  = (bf16*)ws; ws += (size_t)1024 * 1024 * 2;
    bf16* qkb  = (bf16*)ws; ws += (size_t)8192 * 2048 * 2;    // Q|K rows
    bf16* vtb  = (bf16*)ws; ws += (size_t)64 * 64 * 2048 * 2; // V^T per bh
    bf16* aout = (bf16*)ws; ws += (size_t)8192 * 1024 * 2;

    prep_kernel<<<8192 + 4096, 256, 0, stream>>>(x, xb, W_qkv, wtq, W_out, wto);

    gemm256<true, true><<<dim3(12, 32), 512, 0, stream>>>(
        xb, wtq, b_qkv, (void*)qkb, vtb, 8192, 3072, 1024, 2048);
    attn_kernel<<<dim3(64, 16), 256, 0, stream>>>(qkb, vtb, aout);
    gemm_bt<false, false><<<dim3(8, 64), 256, 0, stream>>>(
        aout, wto, b_out, (void*)out, nullptr, 8192, 1024, 1024, 1024);
}

// Round 4
// 227.788 us; speedup vs baseline: 1.0645x; 1.0645x over previous
//
#include <hip/hip_runtime.h>

typedef __bf16 bf16;
typedef __bf16 bf16x4 __attribute__((ext_vector_type(4)));
typedef __bf16 bf16x8 __attribute__((ext_vector_type(8)));
typedef float f32x4 __attribute__((ext_vector_type(4)));

#define T_SEQ 2048
#define QK_LD 2048

extern "C" __device__ float __ocml_native_exp2_f32(float);   // raw v_exp_f32

#define GLOAD16(gp, lp)                                                        \
  __builtin_amdgcn_global_load_lds(                                            \
      (const __attribute__((address_space(1))) unsigned int*)(gp),             \
      (__attribute__((address_space(3))) unsigned int*)(lp), 16, 0, 0)

// ---------------------------------------------------------------------------
// Fused prep (one dispatch, 256-thr blocks):
//   blocks [0, 8192)        : x (fp32, 8192x1024) -> xb bf16
//   blocks [8192, 8192+3072): W_qkv (1024x3072) -> wtq (3072x1024) bf16
//   blocks [+3072, +4096)   : W_out (1024x1024) -> wto (1024x1024) bf16
// ---------------------------------------------------------------------------
__global__ void prep_kernel(const float* __restrict__ x, bf16* __restrict__ xb,
                            const float* __restrict__ Wq, bf16* __restrict__ Wtq,
                            const float* __restrict__ Wo, bf16* __restrict__ Wto) {
    __shared__ float tile[32][33];
    const int t = threadIdx.x;
    if (blockIdx.x < 8192) {
        const int i = (blockIdx.x * 256 + t) * 4;
        const float4 f = *(const float4*)(x + i);
        bf16x4 o;
        o.x = (bf16)f.x; o.y = (bf16)f.y; o.z = (bf16)f.z; o.w = (bf16)f.w;
        *(bf16x4*)(xb + i) = o;
        return;
    }
    const int bid = blockIdx.x - 8192;            // [0, 4096)
    const int xblk = bid & 127, yblk = bid >> 7;  // 128 x 32 tiles of 32x32
    const bool isQ = xblk < 96;
    const float* W = isQ ? Wq : Wo;
    bf16* Wt = isQ ? Wtq : Wto;
    const int C = isQ ? 3072 : 1024;
    const int R = 1024;
    const int bx = (isQ ? xblk : (xblk - 96)) * 32;
    const int by = yblk * 32;
    const int tx = t & 31, ty = t >> 5;
#pragma unroll
    for (int i = 0; i < 32; i += 8)
        tile[ty + i][tx] = W[(size_t)(by + ty + i) * C + bx + tx];
    __syncthreads();
#pragma unroll
    for (int i = 0; i < 32; i += 8)
        Wt[(size_t)(bx + ty + i) * R + by + tx] = (bf16)tile[tx][ty + i];
}

// ---------------------------------------------------------------------------
// Round-3 GEMM: 128x128 tile, BK=64, 4 waves (256 thr), dbuf LDS 64 KiB ->
// TWO BLOCKS PER CU. Post-mortem r0-r2: 256² (128 KiB LDS, 1 blk/CU, 2
// waves/SIMD lockstep) pinned at 24-28% MfmaUtil across three different sync
// schedules — with only one block resident, every pipe (MFMA 2483 cyc,
// ds_read 576, LDS-DMA ~500, VALU ~900, waits) ADDS on the critical path;
// no independent wave exists to overlap them (m114 mechanism starved).
// Fix = occupancy, not schedule: ~160 regs (acc 64 + frags 64) and 64 KiB
// LDS fit 2 independent blocks/CU -> each SIMD hosts 1 wave of each block;
// block X's MFMA covers block Y's stage/read/barrier phases automatically.
// Keeps: round-2 single-barrier K-tile loop, 8-chunk XOR swizzle (conflicts
// 0), global_load_lds staging, old gemm_bt 4-wave epilogue verbatim.
// Grid 1536 blocks = exactly 6/CU (no tail waste); also used for out-proj
// (512 blocks = exactly 2/CU).
// ---------------------------------------------------------------------------
template <bool OUT_BF16, bool SPLIT_V>
__global__ __launch_bounds__(256, 2)
void gemm128(const bf16* __restrict__ A, const bf16* __restrict__ Bt,
             const float* __restrict__ bias, void* __restrict__ Cout,
             bf16* __restrict__ Vtb, int M, int N, int K, int ldC) {
    __shared__ bf16 sm[32768];   // 64 KiB: 2 bufs x (A 8192 + B 8192 elems)

    const int t = threadIdx.x;
    const int lane = t & 63, quad = lane >> 4, l16 = lane & 15;
    const int wave = t >> 6;
    const int wm = (wave >> 1) * 64;
    const int wn = (wave & 1) * 64;
    const long m0 = (long)blockIdx.y * 128;
    const long n0 = (long)blockIdx.x * 128;
    (void)M; (void)N;

    f32x4 acc[4][4] = {};

    // --- staging coords: thread t covers row = t>>3 (0..31), 16B chunk t&7.
    // Stored chunk c' = t&7 holds logical chunk (t&7)^(row&7)  (XOR swizzle
    // applied on the GLOBAL source, LDS dest linear — rule #21).
    // Each GLOAD16 covers 32 rows (256 thr x 16 B = 4 KB); 4 per operand.
    const int srow = t >> 3;
    const int scol = ((t & 7) ^ ((t >> 3) & 7)) * 8;
    const bf16* agp = A  + (m0 + srow) * (long)K + scol;
    const bf16* bgp = Bt + (n0 + srow) * (long)K + scol;
    const long rowK32 = (long)32 * K;

    auto stage = [&](int buf, int kt) {
        bf16* d = sm + buf * 16384 + t * 8;     // wave-uniform base + lane*16B
        const bf16* a = agp + (long)kt * 64;
        const bf16* b = bgp + (long)kt * 64;
        GLOAD16(a,               d);            // A rows  0..31
        GLOAD16(a +     rowK32,  d + 2048);     // A rows 32..63
        GLOAD16(a + 2 * rowK32,  d + 4096);     // A rows 64..95
        GLOAD16(a + 3 * rowK32,  d + 6144);     // A rows 96..127
        GLOAD16(b,               d + 8192);     // B rows  0..31
        GLOAD16(b +     rowK32,  d + 10240);
        GLOAD16(b + 2 * rowK32,  d + 12288);
        GLOAD16(b + 3 * rowK32,  d + 14336);
    };

    // --- fragment LDS offsets (row = 64 bf16 = 8 chunks, XOR-swizzled) -----
    int offA[4][2], offB[4][2];
#pragma unroll
    for (int i = 0; i < 4; ++i)
#pragma unroll
        for (int ks = 0; ks < 2; ++ks) {
            const int rA = wm + i * 16 + l16;
            offA[i][ks] = rA * 64 + (((ks * 4 + quad) ^ (rA & 7)) << 3);
            const int rB = wn + i * 16 + l16;
            offB[i][ks] = 8192 + rB * 64 + (((ks * 4 + quad) ^ (rB & 7)) << 3);
        }

    const int nkt = K >> 6;          // K-tiles of 64

    stage(0, 0);
    asm volatile("s_waitcnt vmcnt(0)" ::: "memory");
    __builtin_amdgcn_s_barrier();
    __builtin_amdgcn_sched_barrier(0);

    for (int kt = 0; kt < nkt; ++kt) {
        const int buf = kt & 1;
        if (kt + 1 < nkt) stage(buf ^ 1, kt + 1);   // prefetch next tile
        const bf16* base_ = sm + buf * 16384;
        bf16x8 fA[2][4], fB[2][4];                  // [ks][i/j]
#pragma unroll
        for (int ks = 0; ks < 2; ++ks)
#pragma unroll
            for (int i = 0; i < 4; ++i) {
                fA[ks][i] = *(const bf16x8*)(base_ + offA[i][ks]);
                fB[ks][i] = *(const bf16x8*)(base_ + offB[i][ks]);
            }
#pragma unroll
        for (int ks = 0; ks < 2; ++ks)
#pragma unroll
            for (int i = 0; i < 4; ++i)
#pragma unroll
                for (int j = 0; j < 4; ++j)   // swapped: D row=n, col=m
                    acc[i][j] = __builtin_amdgcn_mfma_f32_16x16x32_bf16(
                        fB[ks][j], fA[ks][i], acc[i][j], 0, 0, 0);
        if (kt + 1 < nkt) {
            asm volatile("s_waitcnt vmcnt(0)" ::: "memory");
            __builtin_amdgcn_s_barrier();
            __builtin_amdgcn_sched_barrier(0);
        }
    }

    // --- epilogue: old gemm_bt 4-wave mapping verbatim ----------------------
    bf16*  Cb = (bf16*)Cout;
    float* Cf = (float*)Cout;
    const bool vblock = SPLIT_V && (n0 >= 2048);
#pragma unroll
    for (int i = 0; i < 4; ++i) {
        const long gm = m0 + wm + i * 16 + l16;
#pragma unroll
        for (int j = 0; j < 4; ++j) {
            const int nloc = wn + j * 16 + quad * 4;
            const long n = n0 + nloc;
            const float4 bv = *(const float4*)(bias + n);
            float v[4];
#pragma unroll
            for (int r = 0; r < 4; ++r) v[r] = acc[i][j][r] + (&bv.x)[r];
            if (vblock) {
                const int bb = (int)(gm >> 11), tok = (int)(gm & 2047);
                const int nv = (int)(n - 2048);
                const int h = nv >> 6, d0 = nv & 63;
                bf16* dst = Vtb + ((size_t)(bb * 16 + h) * 64 + d0) * T_SEQ + tok;
#pragma unroll
                for (int r = 0; r < 4; ++r) dst[(size_t)r * T_SEQ] = (bf16)v[r];
            } else if (OUT_BF16) {
                bf16x4 o;
#pragma unroll
                for (int r = 0; r < 4; ++r) o[r] = (bf16)v[r];
                *(bf16x4*)(Cb + gm * ldC + n) = o;
            } else {
                float4 o;
#pragma unroll
                for (int r = 0; r < 4; ++r) (&o.x)[r] = v[r];
                *(float4*)(Cf + gm * ldC + n) = o;
            }
        }
    }
}

// ---------------------------------------------------------------------------
// Causal flash attention  [r6/r9 verbatim — best measured ~75 us].
// ---------------------------------------------------------------------------
__global__ __launch_bounds__(256, 3)
void attn_kernel(const bf16* __restrict__ qk, const bf16* __restrict__ vtb,
                 bf16* __restrict__ Out) {
    const int bh = blockIdx.x;
    const int qt = 15 - (int)blockIdx.y;    // heavy tiles first
    const int b = bh >> 4, h = bh & 15;
    const int t = threadIdx.x;
    const int wave = t >> 6, lane = t & 63, quad = lane >> 4, l16 = lane & 15;
    const int wq = wave * 32;
    const int q0 = qt * 128;

    __shared__ bf16 Ks[2][4096];
    __shared__ bf16 VTs[2][4096];
    __shared__ bf16 Ps[8192];

    const bf16* Qg = qk + (size_t)b * T_SEQ * QK_LD + h * 64;
    const bf16* Kg = Qg + 1024;
    const bf16* vth = vtb + (size_t)bh * 64 * T_SEQ;

    for (int c = t; c < 1024; c += 256) {
        const int row = c >> 3, kb = c & 7;
        *(uint4*)(Ps + row * 64 + (((kb ^ (row & 7)) << 3))) =
            *(const uint4*)(Qg + (size_t)(q0 + row) * QK_LD + kb * 8);
    }
    __syncthreads();
    const float qsc = 0.125f * 1.4426950408889634f;
    bf16x8 qf[2][2];
#pragma unroll
    for (int jt = 0; jt < 2; ++jt)
#pragma unroll
        for (int s = 0; s < 2; ++s) {
            const int row = wq + jt * 16 + l16;
            bf16x8 v = *(const bf16x8*)(Ps + row * 64 + (((s * 4 + quad) ^ (row & 7)) << 3));
#pragma unroll
            for (int e = 0; e < 8; ++e) v[e] = (bf16)((float)v[e] * qsc);
            qf[jt][s] = v;
        }

    const int sr = t >> 3;
    const int skb = (t & 7) ^ (sr & 7);
    const bf16* kp0 = Kg + (size_t)sr * QK_LD + skb * 8;
    const bf16* kp1 = kp0 + (size_t)32 * QK_LD;
    const bf16* vp0 = vth + (size_t)sr * T_SEQ + skb * 8;
    const bf16* vp1 = vp0 + (size_t)32 * T_SEQ;

    int offKV[4][2];
#pragma unroll
    for (int it = 0; it < 4; ++it)
#pragma unroll
        for (int s = 0; s < 2; ++s) {
            const int row = it * 16 + l16;
            offKV[it][s] = row * 64 + (((s * 4 + quad) ^ (row & 7)) << 3);
        }

    f32x4 oacc[4][2] = {};
    float lsum[2] = {0.f, 0.f};
    const int nkt = qt * 2 + 2;

    uint4 kr0 = *(const uint4*)kp0, kr1 = *(const uint4*)kp1;
    uint4 vr0 = *(const uint4*)vp0, vr1 = *(const uint4*)vp1;

    for (int kt = 0; kt < nkt; ++kt) {
        const int k0 = kt * 64;
        bf16* kb_ = Ks[kt & 1];
        bf16* vb_ = VTs[kt & 1];
        *(uint4*)(kb_ + t * 8)        = kr0;
        *(uint4*)(kb_ + 2048 + t * 8) = kr1;
        *(uint4*)(vb_ + t * 8)        = vr0;
        *(uint4*)(vb_ + 2048 + t * 8) = vr1;
        __syncthreads();

        if (kt + 1 < nkt) {
            const int kn = k0 + 64;
            kr0 = *(const uint4*)(kp0 + (size_t)kn * QK_LD);
            kr1 = *(const uint4*)(kp1 + (size_t)kn * QK_LD);
            vr0 = *(const uint4*)(vp0 + kn);
            vr1 = *(const uint4*)(vp1 + kn);
        }

        f32x4 sacc[4][2] = {};
#pragma unroll
        for (int s = 0; s < 2; ++s) {
            bf16x8 kf[4];
#pragma unroll
            for (int it = 0; it < 4; ++it)
                kf[it] = *(const bf16x8*)(kb_ + offKV[it][s]);
#pragma unroll
            for (int it = 0; it < 4; ++it)
#pragma unroll
                for (int jt = 0; jt < 2; ++jt)
                    sacc[it][jt] = __builtin_amdgcn_mfma_f32_16x16x32_bf16(kf[it], qf[jt][s], sacc[it][jt], 0, 0, 0);
        }

        const bool need_mask = (kt >= 2 * qt);
#pragma unroll
        for (int it = 0; it < 4; ++it)
#pragma unroll
            for (int jt = 0; jt < 2; ++jt) {
                const int prow = wq + jt * 16 + l16;
                bf16x4 pb;
                if (need_mask) {
                    const int qrow = q0 + prow;
                    const int kbase = k0 + it * 16 + quad * 4;
#pragma unroll
                    for (int r = 0; r < 4; ++r) {
                        const float e = __ocml_native_exp2_f32(sacc[it][jt][r]);
                        const float p = (kbase + r > qrow) ? 0.f : e;
                        lsum[jt] += p;
                        pb[r] = (bf16)p;
                    }
                } else {
#pragma unroll
                    for (int r = 0; r < 4; ++r) {
                        const float p = __ocml_native_exp2_f32(sacc[it][jt][r]);
                        lsum[jt] += p;
                        pb[r] = (bf16)p;
                    }
                }
                *(bf16x4*)(Ps + prow * 64 +
                           (((it * 2 + (quad >> 1)) ^ (prow & 7)) << 3) + ((quad & 1) << 2)) = pb;
            }

#pragma unroll
        for (int s2 = 0; s2 < 2; ++s2) {
            bf16x8 vf[4], pf[2];
#pragma unroll
            for (int it2 = 0; it2 < 4; ++it2)
                vf[it2] = *(const bf16x8*)(vb_ + offKV[it2][s2]);
#pragma unroll
            for (int jt = 0; jt < 2; ++jt) {
                const int prow = wq + jt * 16 + l16;
                pf[jt] = *(const bf16x8*)(Ps + prow * 64 + (((s2 * 4 + quad) ^ (prow & 7)) << 3));
            }
#pragma unroll
            for (int it2 = 0; it2 < 4; ++it2)
#pragma unroll
                for (int jt = 0; jt < 2; ++jt)
                    oacc[it2][jt] = __builtin_amdgcn_mfma_f32_16x16x32_bf16(vf[it2], pf[jt], oacc[it2][jt], 0, 0, 0);
        }
    }

    float inv[2];
#pragma unroll
    for (int jt = 0; jt < 2; ++jt) {
        float l = lsum[jt];
        l += __shfl_xor(l, 16);
        l += __shfl_xor(l, 32);
        inv[jt] = 1.0f / l;
    }
#pragma unroll
    for (int it2 = 0; it2 < 4; ++it2)
#pragma unroll
        for (int jt = 0; jt < 2; ++jt) {
            bf16x4 ob;
#pragma unroll
            for (int r = 0; r < 4; ++r) ob[r] = (bf16)(oacc[it2][jt][r] * inv[jt]);
            const int qrow = q0 + wq + jt * 16 + l16;
            const int dcol = h * 64 + it2 * 16 + quad * 4;
            *(bf16x4*)&Out[(size_t)(b * T_SEQ + qrow) * 1024 + dcol] = ob;
        }
}

// ---------------------------------------------------------------------------
extern "C" void kernel_launch(void* const* d_in, const int* in_sizes, int n_in,
                              void* d_out, int out_size, void* d_ws, size_t ws_size,
                              hipStream_t stream) {
    const float* x     = (const float*)d_in[0];
    const float* W_qkv = (const float*)d_in[1];
    const float* b_qkv = (const float*)d_in[2];
    const float* W_out = (const float*)d_in[3];
    const float* b_out = (const float*)d_in[4];
    float* out = (float*)d_out;

    char* ws = (char*)d_ws;
    bf16* xb   = (bf16*)ws; ws += (size_t)8192 * 1024 * 2;
    bf16* wtq  = (bf16*)ws; ws += (size_t)3072 * 1024 * 2;
    bf16* wto  = (bf16*)ws; ws += (size_t)1024 * 1024 * 2;
    bf16* qkb  = (bf16*)ws; ws += (size_t)8192 * 2048 * 2;    // Q|K rows
    bf16* vtb  = (bf16*)ws; ws += (size_t)64 * 64 * 2048 * 2; // V^T per bh
    bf16* aout = (bf16*)ws; ws += (size_t)8192 * 1024 * 2;

    prep_kernel<<<8192 + 4096, 256, 0, stream>>>(x, xb, W_qkv, wtq, W_out, wto);

    gemm128<true, true><<<dim3(24, 64), 256, 0, stream>>>(
        xb, wtq, b_qkv, (void*)qkb, vtb, 8192, 3072, 1024, 2048);
    attn_kernel<<<dim3(64, 16), 256, 0, stream>>>(qkb, vtb, aout);
    gemm128<false, false><<<dim3(8, 64), 256, 0, stream>>>(
        aout, wto, b_out, (void*)out, nullptr, 8192, 1024, 1024, 1024);
}